// Round 1
// baseline (144.897 us; speedup 1.0000x reference)
//
#include <hip/hip_runtime.h>

#define EPS 1e-7f

constexpr int B = 16;
constexpr int N = 512 * 1024;          // elements per batch (C=1)
constexpr int BLOCKS_PER_BATCH = 64;
constexpr int THREADS = 256;
// ws layout: per batch 8 doubles: [Sx, Sx2, Ss, Ss2, Sxs, Sf, Sxf, KLD]
constexpr int WS_DOUBLES = B * 8;

__global__ void zero_ws_kernel(double* ws) {
    int i = blockIdx.x * blockDim.x + threadIdx.x;
    if (i < WS_DOUBLES) ws[i] = 0.0;
}

__device__ __forceinline__ float wave_reduce(float v) {
    #pragma unroll
    for (int off = 32; off > 0; off >>= 1) v += __shfl_down(v, off, 64);
    return v;
}

__global__ __launch_bounds__(THREADS) void pass1_kernel(
    const float* __restrict__ inp, const float* __restrict__ sal,
    const float* __restrict__ fix, const float* __restrict__ wgt,
    double* __restrict__ ws) {
    const int b = blockIdx.y;
    const float4* ip = (const float4*)(inp + (size_t)b * N);
    const float4* sp = (const float4*)(sal + (size_t)b * N);
    const float4* fp = (const float4*)(fix + (size_t)b * N);
    const float4* wp = (const float4*)wgt;
    const int n4 = N / 4;

    float sx = 0.f, sx2 = 0.f, ss = 0.f, ss2 = 0.f, sxs = 0.f, sf = 0.f, sxf = 0.f;
    for (int i = blockIdx.x * blockDim.x + threadIdx.x; i < n4;
         i += blockDim.x * gridDim.x) {
        float4 vi = ip[i], vs = sp[i], vf = fp[i], vw = wp[i];
        float xi[4] = {vi.x, vi.y, vi.z, vi.w};
        float si[4] = {vs.x, vs.y, vs.z, vs.w};
        float fi[4] = {vf.x, vf.y, vf.z, vf.w};
        float wi[4] = {vw.x, vw.y, vw.z, vw.w};
        #pragma unroll
        for (int k = 0; k < 4; k++) {
            float x = xi[k] * wi[k];
            float s = si[k] * wi[k];
            float f = fi[k] * wi[k];
            sx  += x;     sx2 += x * x;
            ss  += s;     ss2 += s * s;
            sxs += x * s;
            sf  += f;     sxf += x * f;
        }
    }

    // wave(64) reduce, then cross-wave via LDS in double, then global atomics
    sx = wave_reduce(sx);   sx2 = wave_reduce(sx2);
    ss = wave_reduce(ss);   ss2 = wave_reduce(ss2);
    sxs = wave_reduce(sxs);
    sf = wave_reduce(sf);   sxf = wave_reduce(sxf);

    __shared__ double part[THREADS / 64][7];
    const int lane = threadIdx.x & 63;
    const int wave = threadIdx.x >> 6;
    if (lane == 0) {
        part[wave][0] = (double)sx;  part[wave][1] = (double)sx2;
        part[wave][2] = (double)ss;  part[wave][3] = (double)ss2;
        part[wave][4] = (double)sxs;
        part[wave][5] = (double)sf;  part[wave][6] = (double)sxf;
    }
    __syncthreads();
    if (threadIdx.x < 7) {
        double t = 0.0;
        #pragma unroll
        for (int wv = 0; wv < THREADS / 64; wv++) t += part[wv][threadIdx.x];
        atomicAdd(&ws[b * 8 + threadIdx.x], t);
    }
}

__global__ __launch_bounds__(THREADS) void pass2_kernel(
    const float* __restrict__ inp, const float* __restrict__ sal,
    const float* __restrict__ wgt, double* __restrict__ ws) {
    const int b = blockIdx.y;
    const double* acc = ws + b * 8;
    const float invSx = (float)(1.0 / acc[0]);
    const float invSs = (float)(1.0 / acc[2]);

    const float4* ip = (const float4*)(inp + (size_t)b * N);
    const float4* sp = (const float4*)(sal + (size_t)b * N);
    const float4* wp = (const float4*)wgt;
    const int n4 = N / 4;

    float kacc = 0.f;
    for (int i = blockIdx.x * blockDim.x + threadIdx.x; i < n4;
         i += blockDim.x * gridDim.x) {
        float4 vi = ip[i], vs = sp[i], vw = wp[i];
        float xi[4] = {vi.x, vi.y, vi.z, vi.w};
        float si[4] = {vs.x, vs.y, vs.z, vs.w};
        float wi[4] = {vw.x, vw.y, vw.z, vw.w};
        #pragma unroll
        for (int k = 0; k < 4; k++) {
            float xp = xi[k] * wi[k] * invSx;   // normalized x'
            float yp = si[k] * wi[k] * invSs;   // normalized y'
            kacc += yp * __logf(yp / (xp + EPS) + EPS) ;
        }
    }

    kacc = wave_reduce(kacc);
    __shared__ double part[THREADS / 64];
    const int lane = threadIdx.x & 63;
    const int wave = threadIdx.x >> 6;
    if (lane == 0) part[wave] = (double)kacc;
    __syncthreads();
    if (threadIdx.x == 0) {
        double t = 0.0;
        #pragma unroll
        for (int wv = 0; wv < THREADS / 64; wv++) t += part[wv];
        atomicAdd(&ws[b * 8 + 7], t);
    }
}

__global__ void finalize_kernel(const double* __restrict__ ws,
                                float* __restrict__ out) {
    if (blockIdx.x == 0 && threadIdx.x == 0) {
        double nss_sum = 0.0, kld_sum = 0.0, cc_sum = 0.0;
        const double n = (double)N;
        for (int b = 0; b < B; b++) {
            const double* a = ws + b * 8;
            const double Sx = a[0], Sx2 = a[1], Ss = a[2], Ss2 = a[3];
            const double Sxs = a[4], Sf = a[5], Sxf = a[6], K = a[7];
            // NSS: mu/sd of x (ddof=1), dot with f, normalized by sum f
            double mu = Sx / n;
            double var = (Sx2 - Sx * Sx / n) / (n - 1.0);
            double sd = sqrt(var);
            double nss = ((Sxf - mu * Sf) / (sd + (double)EPS)) / (Sf + (double)EPS);
            // CC on normalized x'=x/Sx, y'=s/Ss (their sums are exactly 1)
            double sum_prod = Sxs / (Sx * Ss);
            double sum_x2 = Sx2 / (Sx * Sx);
            double sum_y2 = Ss2 / (Ss * Ss);
            double num = sum_prod - 1.0 / n;
            double den = sqrt((sum_x2 - 1.0 / n) * (sum_y2 - 1.0 / n));
            double cc = num / (den + (double)EPS);
            nss_sum += nss;
            kld_sum += K;
            cc_sum += cc;
        }
        double loss = (-0.1 * nss_sum + kld_sum - 0.1 * cc_sum) / (double)B;
        out[0] = (float)loss;
    }
}

extern "C" void kernel_launch(void* const* d_in, const int* in_sizes, int n_in,
                              void* d_out, int out_size, void* d_ws, size_t ws_size,
                              hipStream_t stream) {
    const float* inp = (const float*)d_in[0];
    const float* sal = (const float*)d_in[1];
    const float* fix = (const float*)d_in[2];
    const float* wgt = (const float*)d_in[3];
    float* out = (float*)d_out;
    double* ws = (double*)d_ws;

    zero_ws_kernel<<<1, 128, 0, stream>>>(ws);
    dim3 grid(BLOCKS_PER_BATCH, B);
    pass1_kernel<<<grid, THREADS, 0, stream>>>(inp, sal, fix, wgt, ws);
    pass2_kernel<<<grid, THREADS, 0, stream>>>(inp, sal, wgt, ws);
    finalize_kernel<<<1, 64, 0, stream>>>(ws, out);
}